// Round 11
// baseline (353.696 us; speedup 1.0000x reference)
//
#include <hip/hip_runtime.h>

typedef __bf16 v8bf __attribute__((ext_vector_type(8)));
typedef __bf16 v4bf __attribute__((ext_vector_type(4)));
typedef float floatx4 __attribute__((ext_vector_type(4)));

#define MFMA16(a, b, c) __builtin_amdgcn_mfma_f32_16x16x32_bf16(a, b, c, 0, 0, 0)
// async global->LDS, 16B/lane; LDS dest = wave-uniform base + lane*16
#define GLL16(gp, lp)                                                        \
    __builtin_amdgcn_global_load_lds(                                        \
        (const __attribute__((address_space(1))) void*)(gp),                 \
        (__attribute__((address_space(3))) void*)(lp), 16, 0, 0)
// counted vmcnt + raw barrier (asm w/ memory clobber: no compiler drain,
// no load motion across)
#define VMW(n) asm volatile("s_waitcnt vmcnt(" #n ")" ::: "memory")
#define BARRIER() asm volatile("s_barrier" ::: "memory")

// ------------------- prep: cast x -> bf16  AND  transpose/cast weights
__global__ void prep(const float* __restrict__ x, __bf16* __restrict__ xb, int n4,
                     const float* __restrict__ W0, const float* __restrict__ W1,
                     const float* __restrict__ W2, const float* __restrict__ W3,
                     __bf16* __restrict__ dqkv, __bf16* __restrict__ dwo) {
    __shared__ __bf16 tile[64][65];
    int b = blockIdx.x;
    if (b < 640) {                         // ---- transW job (16 x 40)
        int k0 = (b & 15) * 64;
        int byy = b >> 4;
        bool isO = byy >= 24;
        int c0 = (isO ? byy - 24 : byy) * 64;
        for (int i = threadIdx.x; i < 4096; i += 256) {
            int k = i >> 6, c = i & 63;
            int gc = c0 + c;
            float v;
            if (isO)            v = W3[(k0 + k) * 1024 + gc];
            else if (gc < 1024) v = W0[(k0 + k) * 1024 + gc];
            else if (gc < 1280) v = W1[(k0 + k) * 256 + gc - 1024];
            else                v = W2[(k0 + k) * 256 + gc - 1280];
            tile[c][k] = (__bf16)v;
        }
        __syncthreads();
        __bf16* dst = isO ? dwo : dqkv;
        for (int i = threadIdx.x; i < 4096; i += 256) {
            int c = i >> 6, k = i & 63;
            dst[(c0 + c) * 1024 + k0 + k] = tile[c][k];
        }
    } else {                               // ---- cast_x job (grid-stride)
        int i = (b - 640) * 256 + threadIdx.x;
        int stride = (gridDim.x - 640) * 256;
        for (; i < n4; i += stride) {
            float4 v = ((const float4*)x)[i];
            v4bf o;
            o[0] = (__bf16)v.x; o[1] = (__bf16)v.y; o[2] = (__bf16)v.z; o[3] = (__bf16)v.w;
            ((v4bf*)xb)[i] = o;
        }
    }
}

// -------------------- GEMM (NT, bf16 MFMA), 4-wave blocks, 2 blocks/CU
// R5-proven config: 128x256 tile, 72KB LDS (3 slots), 2 barrier chains/CU,
// depth-2 GLL pipeline with counted VMW(12).  63.6us / MfmaUtil 33%.
// R6 LESSON: (256,3) -> regs capped at 168 -> acc spills (2x dur).
// R8/R9 LESSON: fused norm epilogue costs +13us (per-execution overhead).
// Keep this kernel EXACTLY R5.
template <typename OUT>
__global__ __launch_bounds__(256, 2) void gemm_bt(const __bf16* __restrict__ A,
                                                  const __bf16* __restrict__ B,
                                                  OUT* __restrict__ C, int N) {
    constexpr int SLAB = (128 + 256) * 32;           // 12288 elems = 24KB
    __shared__ __attribute__((aligned(16))) __bf16 smem[3 * SLAB];  // 72KB
    const int t = threadIdx.x, lane = t & 63, w = t >> 6;
    const int gx = gridDim.x;
    const int nwg = gx * gridDim.y;
    const int id = blockIdx.y * gx + blockIdx.x;
    const int swz = (id & 7) * (nwg >> 3) + (id >> 3);
    const int m0 = (swz / gx) * 128, n0 = (swz % gx) * 256;
    const int wn = w * 64;
    const int rl = lane >> 2;
    const int gl = (lane & 3) ^ ((lane >> 3) & 3);
    const __bf16* pA = A + (long)(m0 + w * 32 + rl) * 1024 + gl * 8;
    const __bf16* pB = B + (long)(n0 + w * 64 + rl) * 1024 + gl * 8;
    const int lr = lane & 15, quad = lane >> 4, m = lane & 15;
    const int ga = ((quad ^ ((lr >> 1) & 3)) * 8);
    floatx4 acc[8][4] = {};

    auto STAGE = [&](int s) {
        __bf16* base = smem + (s % 3) * SLAB;
        const __bf16* sa = pA + s * 32;
        const __bf16* sb = pB + s * 32;
        GLL16(sa,             base + w * 1024);
        GLL16(sa + 16 * 1024, base + w * 1024 + 512);
        __bf16* bb = base + 4096;
        GLL16(sb,             bb + w * 2048);
        GLL16(sb + 16 * 1024, bb + w * 2048 + 512);
        GLL16(sb + 32 * 1024, bb + w * 2048 + 1024);
        GLL16(sb + 48 * 1024, bb + w * 2048 + 1536);
    };
    auto COMPUTE = [&](int s) {
        const __bf16* As_ = smem + (s % 3) * SLAB;
        const __bf16* Bs_ = As_ + 4096;
        v8bf af[8], bq[4];
#pragma unroll
        for (int i = 0; i < 8; ++i)
            af[i] = *(const v8bf*)(As_ + (i * 16 + lr) * 32 + ga);
#pragma unroll
        for (int j = 0; j < 4; ++j)
            bq[j] = *(const v8bf*)(Bs_ + (wn + j * 16 + lr) * 32 + ga);
        __builtin_amdgcn_s_setprio(1);
#pragma unroll
        for (int i = 0; i < 8; ++i)
#pragma unroll
            for (int j = 0; j < 4; ++j)
                acc[i][j] = MFMA16(af[i], bq[j], acc[i][j]);
        __builtin_amdgcn_s_setprio(0);
    };

    STAGE(0); STAGE(1);
#pragma unroll 1
    for (int s = 0; s < 30; ++s) {
        STAGE(s + 2);
        VMW(12);
        BARRIER();
        COMPUTE(s);
        BARRIER();
    }
    VMW(6);  BARRIER(); COMPUTE(30); BARRIER();
    VMW(0);  BARRIER(); COMPUTE(31);
    __syncthreads();

    const int row2 = lane >> 2, cb = lane & 3;
    if constexpr (sizeof(OUT) == 2) {
        __bf16* tile = smem + w * (16 * 68);
#pragma unroll
        for (int i = 0; i < 8; ++i) {
#pragma unroll
            for (int j = 0; j < 4; ++j)
#pragma unroll
                for (int r = 0; r < 4; ++r)
                    tile[(quad * 4 + r) * 68 + j * 16 + m] = (__bf16)acc[i][j][r];
            __bf16* dst = (__bf16*)C + (long)(m0 + i * 16 + row2) * N + n0 + wn + cb * 16;
            *(v8bf*)dst = *(const v8bf*)(&tile[row2 * 68 + cb * 16]);
            *(v8bf*)(dst + 8) = *(const v8bf*)(&tile[row2 * 68 + cb * 16 + 8]);
        }
    } else {
        float* tile = (float*)smem + w * (16 * 66);
#pragma unroll
        for (int i = 0; i < 8; ++i) {
#pragma unroll
            for (int j = 0; j < 4; ++j)
#pragma unroll
                for (int r = 0; r < 4; ++r)
                    tile[(quad * 4 + r) * 66 + j * 16 + m] = acc[i][j][r];
            float* dst = (float*)C + (long)(m0 + i * 16 + row2) * N + n0 + wn + cb * 16;
#pragma unroll
            for (int c = 0; c < 4; ++c)
                *(floatx4*)(dst + c * 4) = *(const floatx4*)(&tile[row2 * 66 + cb * 16 + c * 4]);
        }
    }
}

// ---------------------------------------------------------------- attention
// R11: one block per (n,h) processing BOTH half-tiles (R7 ran 2 blocks per
// (n,h); 8 blocks shared each (n,hk) K -- K-norm+staging executed 8x, V^T
// staged 2x).  K and V^T now live in SEPARATE LDS regions (32KB+32KB+10KB
// Ps = 74KB -> 2 blocks/CU), staged once under a single barrier; the
// half-loop then only READS LDS (no barriers between halves; Ps per-wave).
// All inner pieces verbatim from the proven R7/R5 code: shfl K-norm,
// V^T slot perm = sgi ^ (hd&7) ^ (hd>>3), in-register Q-norm (2 shfls),
// fma-folded bounded softmax.
__global__ __launch_bounds__(512) void attn_kernel(const __bf16* __restrict__ qkv,
                                                   const float* __restrict__ rc,
                                                   const float* __restrict__ rs,
                                                   const float* __restrict__ qsc,
                                                   const float* __restrict__ ksc,
                                                   __bf16* __restrict__ O) {
    __shared__ __attribute__((aligned(16))) __bf16 Ks[256 * 64];
    __shared__ __attribute__((aligned(16))) __bf16 Vt[64 * 256];
    __shared__ __attribute__((aligned(16))) __bf16 Ps[8][16][40];
    const int bx = blockIdx.x;
    const int n = bx >> 4, h = bx & 15, hk = h >> 2;
    const int t = threadIdx.x, lane = t & 63, w = t >> 6;
    const int m = lane & 15, quad = lane >> 4;

    // ---- stage K with fused rmsnorm+rope (R7 shfl version), once ----
    for (int p = 0; p < 4; ++p) {
        int l = t + p * 512;
        int s = l >> 3, cg = l & 7;
        v8bf kv = *(const v8bf*)(qkv + (long)(n * 256 + s) * 1536 + 1024 + hk * 64 + cg * 8);
        float f[8], ss2 = 0.f;
#pragma unroll
        for (int j = 0; j < 8; ++j) { f[j] = (float)kv[j]; ss2 += f[j] * f[j]; }
        ss2 += __shfl_xor(ss2, 1);
        ss2 += __shfl_xor(ss2, 2);
        ss2 += __shfl_xor(ss2, 4);
        float krr = rsqrtf(ss2 * (1.f / 64.f) + 1e-6f);
        float vs[8];
#pragma unroll
        for (int j = 0; j < 8; ++j) vs[j] = f[j] * krr * ksc[cg * 8 + j];
        v8bf outv;
#pragma unroll
        for (int j = 0; j < 8; ++j) {
            float pv = __shfl_xor(vs[j], 4);          // partner hd^32
            int hd = cg * 8 + j;
            float c = rc[s * 32 + (hd & 31)], sn = rs[s * 32 + (hd & 31)];
            outv[j] = (__bf16)((cg < 4) ? (vs[j] * c - pv * sn)
                                        : (vs[j] * c + pv * sn));
        }
        *(v8bf*)(&Ks[s * 64 + ((cg ^ (s & 7)) * 8)]) = outv;
    }
    // ---- stage V^T (R5 perm), once ----
    for (int p = 0; p < 4; ++p) {
        int l = t + p * 512;
        int s = l >> 3, cg = l & 7;
        v8bf vv = *(const v8bf*)(qkv + (long)(n * 256 + s) * 1536 + 1280 + hk * 64 + cg * 8);
#pragma unroll
        for (int j = 0; j < 8; ++j)
            Vt[(cg * 8 + j) * 256 + (((s >> 3) ^ j ^ cg) * 8) + (s & 7)] = vv[j];
    }
    __syncthreads();

    // ---- both half-tiles, reusing staged K/V (read-only; no barriers) ----
#pragma unroll 1
    for (int half = 0; half < 2; ++half) {
        const int srow = half * 128 + w * 16 + m;
        const __bf16* qp = qkv + (long)(n * 256 + srow) * 1536 + h * 64 + quad * 8;
        v8bf qr0 = *(const v8bf*)(qp);
        v8bf qr1 = *(const v8bf*)(qp + 32);
        float f0[8], f1[8], ss = 0.f;
#pragma unroll
        for (int j = 0; j < 8; ++j) {
            f0[j] = (float)qr0[j]; f1[j] = (float)qr1[j];
            ss += f0[j] * f0[j] + f1[j] * f1[j];
        }
        ss += __shfl_xor(ss, 16);
        ss += __shfl_xor(ss, 32);
        float rr = rsqrtf(ss * (1.f / 64.f) + 1e-6f);
        v8bf qa0, qa1;
#pragma unroll
        for (int j = 0; j < 8; ++j) {
            int hd = quad * 8 + j;
            float t1 = f0[j] * rr * qsc[hd];
            float t2 = f1[j] * rr * qsc[32 + hd];
            float c = rc[srow * 32 + hd], sn = rs[srow * 32 + hd];
            qa0[j] = (__bf16)(t1 * c - t2 * sn);
            qa1[j] = (__bf16)(t2 * c + t1 * sn);
        }

        floatx4 sc[16];
#pragma unroll
        for (int ti = 0; ti < 16; ++ti) {
            int kr = ti * 16 + m;
            v8bf b0 = *(const v8bf*)(&Ks[kr * 64 + ((quad ^ (kr & 7)) * 8)]);
            v8bf b1 = *(const v8bf*)(&Ks[kr * 64 + (((quad + 4) ^ (kr & 7)) * 8)]);
            floatx4 a = {0.f, 0.f, 0.f, 0.f};
            a = MFMA16(qa0, b0, a);
            a = MFMA16(qa1, b1, a);
            sc[ti] = a;
        }

        // p = exp(50*tanh(v*0.0025)); bounded -> no max-subtract
        const int qbase = half * 128 + w * 16 + quad * 4;
        float sum[4] = {0.f, 0.f, 0.f, 0.f};
#pragma unroll
        for (int ti = 0; ti < 16; ++ti)
#pragma unroll
            for (int r = 0; r < 4; ++r) {
                float v = sc[ti][r];
                float e = __builtin_amdgcn_exp2f(v * 0.0072134752f);
                float p = __builtin_amdgcn_exp2f(
                    fmaf(__builtin_amdgcn_rcpf(e + 1.f), -144.269504f, 72.134752f));
                if (ti == 15 && (qbase + r) < 240) p = 0.f;
                sc[ti][r] = p;
                sum[r] += p;
            }
        float inv[4];
#pragma unroll
        for (int r = 0; r < 4; ++r) {
#pragma unroll
            for (int msk = 1; msk < 16; msk <<= 1) sum[r] += __shfl_xor(sum[r], msk);
            inv[r] = __builtin_amdgcn_rcpf(sum[r]);
        }

        floatx4 oacc[4] = {};
#pragma unroll
        for (int kc = 0; kc < 8; ++kc) {
#pragma unroll
            for (int ht = 0; ht < 2; ++ht) {
                int ti = kc * 2 + ht;
#pragma unroll
                for (int r = 0; r < 4; ++r)
                    Ps[w][quad * 4 + r][ht * 16 + m] = (__bf16)sc[ti][r];
            }
            v8bf pa = *(const v8bf*)(&Ps[w][m][quad * 8]);
#pragma unroll
            for (int ct = 0; ct < 4; ++ct) {
                int hd = ct * 16 + m;
                int sg = kc * 4 + quad;
                int sl = (sg ^ (hd & 7) ^ (hd >> 3)) & 31;
                v8bf vb = *(const v8bf*)(&Vt[hd * 256 + sl * 8]);
                oacc[ct] = MFMA16(pa, vb, oacc[ct]);
            }
        }
#pragma unroll
        for (int ct = 0; ct < 4; ++ct)
#pragma unroll
            for (int r = 0; r < 4; ++r) {
                int qrow = half * 128 + w * 16 + quad * 4 + r;
                O[(long)(n * 256 + qrow) * 1024 + h * 64 + ct * 16 + m] =
                    (__bf16)(oacc[ct][r] * inv[r]);
            }
    }
}

// ---------------------------------------------------------------- launch
extern "C" void kernel_launch(void* const* d_in, const int* in_sizes, int n_in,
                              void* d_out, int out_size, void* d_ws, size_t ws_size,
                              hipStream_t stream) {
    const float* x  = (const float*)d_in[0];
    const float* rc = (const float*)d_in[2];
    const float* rs = (const float*)d_in[3];
    const float* Wq = (const float*)d_in[4];
    const float* Wk = (const float*)d_in[5];
    const float* Wv = (const float*)d_in[6];
    const float* Wo = (const float*)d_in[7];
    const float* qs = (const float*)d_in[8];
    const float* ks = (const float*)d_in[9];
    float* out = (float*)d_out;
    char* ws = (char*)d_ws;

    __bf16* x_bf    = (__bf16*)(ws);                       // 32MB
    __bf16* WqkvT   = (__bf16*)(ws + (32l << 20));         // 3MB  [1536][1024]
    __bf16* WoT     = (__bf16*)(ws + (35l << 20));         // 2MB  [1024][1024]
    __bf16* qkv_bf  = (__bf16*)(ws + (37l << 20));         // 48MB [16384][1536]
    __bf16* attn_bf = (__bf16*)(ws + (93l << 20));         // 32MB [16384][1024]

    // prep: blocks [0,640) transpose/cast weights, [640,4736) cast x
    prep<<<4736, 256, 0, stream>>>(x, x_bf, 16777216 / 4,
                                   Wq, Wk, Wv, Wo, WqkvT, WoT);
    gemm_bt<__bf16><<<dim3(6, 128), 256, 0, stream>>>(x_bf, WqkvT, qkv_bf, 1536);
    // attn: 1024 blocks = one per (n,h), both halves per block = 2 exact
    // rounds at 2 blocks/CU
    attn_kernel<<<1024, 512, 0, stream>>>(qkv_bf, rc, rs, qs, ks, attn_bf);
    gemm_bt<float><<<dim3(4, 128), 256, 0, stream>>>(attn_bf, WoT, out, 1024);
}

// Round 12
// 305.237 us; speedup vs baseline: 1.1588x; 1.1588x over previous
//
#include <hip/hip_runtime.h>

typedef __bf16 v8bf __attribute__((ext_vector_type(8)));
typedef __bf16 v4bf __attribute__((ext_vector_type(4)));
typedef float floatx4 __attribute__((ext_vector_type(4)));

#define MFMA16(a, b, c) __builtin_amdgcn_mfma_f32_16x16x32_bf16(a, b, c, 0, 0, 0)
// async global->LDS, 16B/lane; LDS dest = wave-uniform base + lane*16
#define GLL16(gp, lp)                                                        \
    __builtin_amdgcn_global_load_lds(                                        \
        (const __attribute__((address_space(1))) void*)(gp),                 \
        (__attribute__((address_space(3))) void*)(lp), 16, 0, 0)
// counted vmcnt + raw barrier (asm w/ memory clobber: no compiler drain,
// no load motion across)
#define VMW(n) asm volatile("s_waitcnt vmcnt(" #n ")" ::: "memory")
#define BARRIER() asm volatile("s_barrier" ::: "memory")

// ------------------- prep: cast x -> bf16  AND  transpose/cast weights
__global__ void prep(const float* __restrict__ x, __bf16* __restrict__ xb, int n4,
                     const float* __restrict__ W0, const float* __restrict__ W1,
                     const float* __restrict__ W2, const float* __restrict__ W3,
                     __bf16* __restrict__ dqkv, __bf16* __restrict__ dwo) {
    __shared__ __bf16 tile[64][65];
    int b = blockIdx.x;
    if (b < 640) {                         // ---- transW job (16 x 40)
        int k0 = (b & 15) * 64;
        int byy = b >> 4;
        bool isO = byy >= 24;
        int c0 = (isO ? byy - 24 : byy) * 64;
        for (int i = threadIdx.x; i < 4096; i += 256) {
            int k = i >> 6, c = i & 63;
            int gc = c0 + c;
            float v;
            if (isO)            v = W3[(k0 + k) * 1024 + gc];
            else if (gc < 1024) v = W0[(k0 + k) * 1024 + gc];
            else if (gc < 1280) v = W1[(k0 + k) * 256 + gc - 1024];
            else                v = W2[(k0 + k) * 256 + gc - 1280];
            tile[c][k] = (__bf16)v;
        }
        __syncthreads();
        __bf16* dst = isO ? dwo : dqkv;
        for (int i = threadIdx.x; i < 4096; i += 256) {
            int c = i >> 6, k = i & 63;
            dst[(c0 + c) * 1024 + k0 + k] = tile[c][k];
        }
    } else {                               // ---- cast_x job (grid-stride)
        int i = (b - 640) * 256 + threadIdx.x;
        int stride = (gridDim.x - 640) * 256;
        for (; i < n4; i += stride) {
            float4 v = ((const float4*)x)[i];
            v4bf o;
            o[0] = (__bf16)v.x; o[1] = (__bf16)v.y; o[2] = (__bf16)v.z; o[3] = (__bf16)v.w;
            ((v4bf*)xb)[i] = o;
        }
    }
}

// -------------------- GEMM (NT, bf16 MFMA), 4-wave blocks, 2 blocks/CU
// R5-proven config: 128x256 tile, 72KB LDS (3 slots), 2 barrier chains/CU,
// depth-2 GLL pipeline with counted VMW(12).  63.6us / MfmaUtil 33%.
// R6/R11 LESSON: forcing >2 blocks/CU or merging work that needs >128 live
// VGPR at 2-blocks/CU spills acc to scratch (WRITE_SIZE 3-4x).  Keep
// (256,2) geometry.
// R12: NORM epilogue applied ONLY to the K tile (n0==1024; 128 of 768
// blocks).  R8 measured the full Q+K epilogue-norm (5/6 of blocks) at
// +14.4us; scaling to 1/6 of blocks ~= +2-3us makespan, and it removes the
// 8x-duplicated K-norm from attn (its main VALU cost).  Q-norm stays in
// attn (in-register, 2 shfls -- cheap).  rc/rs staged via LDS (R9,
// measured no-spill).
template <bool NORM, typename OUT>
__global__ __launch_bounds__(256, 2) void gemm_bt(const __bf16* __restrict__ A,
                                                  const __bf16* __restrict__ B,
                                                  OUT* __restrict__ C, int N,
                                                  const float* __restrict__ rc,
                                                  const float* __restrict__ rs,
                                                  const float* __restrict__ ksc) {
    constexpr int SLAB = (128 + 256) * 32;           // 12288 elems = 24KB
    __shared__ __attribute__((aligned(16))) __bf16 smem[3 * SLAB];  // 72KB
    const int t = threadIdx.x, lane = t & 63, w = t >> 6;
    const int gx = gridDim.x;
    const int nwg = gx * gridDim.y;
    const int id = blockIdx.y * gx + blockIdx.x;
    const int swz = (id & 7) * (nwg >> 3) + (id >> 3);
    const int m0 = (swz / gx) * 128, n0 = (swz % gx) * 256;
    const int wn = w * 64;
    const int rl = lane >> 2;
    const int gl = (lane & 3) ^ ((lane >> 3) & 3);
    const __bf16* pA = A + (long)(m0 + w * 32 + rl) * 1024 + gl * 8;
    const __bf16* pB = B + (long)(n0 + w * 64 + rl) * 1024 + gl * 8;
    const int lr = lane & 15, quad = lane >> 4, m = lane & 15;
    const int ga = ((quad ^ ((lr >> 1) & 3)) * 8);
    floatx4 acc[8][4] = {};

    auto STAGE = [&](int s) {
        __bf16* base = smem + (s % 3) * SLAB;
        const __bf16* sa = pA + s * 32;
        const __bf16* sb = pB + s * 32;
        GLL16(sa,             base + w * 1024);
        GLL16(sa + 16 * 1024, base + w * 1024 + 512);
        __bf16* bb = base + 4096;
        GLL16(sb,             bb + w * 2048);
        GLL16(sb + 16 * 1024, bb + w * 2048 + 512);
        GLL16(sb + 32 * 1024, bb + w * 2048 + 1024);
        GLL16(sb + 48 * 1024, bb + w * 2048 + 1536);
    };
    auto COMPUTE = [&](int s) {
        const __bf16* As_ = smem + (s % 3) * SLAB;
        const __bf16* Bs_ = As_ + 4096;
        v8bf af[8], bq[4];
#pragma unroll
        for (int i = 0; i < 8; ++i)
            af[i] = *(const v8bf*)(As_ + (i * 16 + lr) * 32 + ga);
#pragma unroll
        for (int j = 0; j < 4; ++j)
            bq[j] = *(const v8bf*)(Bs_ + (wn + j * 16 + lr) * 32 + ga);
        __builtin_amdgcn_s_setprio(1);
#pragma unroll
        for (int i = 0; i < 8; ++i)
#pragma unroll
            for (int j = 0; j < 4; ++j)
                acc[i][j] = MFMA16(af[i], bq[j], acc[i][j]);
        __builtin_amdgcn_s_setprio(0);
    };

    STAGE(0); STAGE(1);
#pragma unroll 1
    for (int s = 0; s < 30; ++s) {
        STAGE(s + 2);
        VMW(12);
        BARRIER();
        COMPUTE(s);
        BARRIER();
    }
    VMW(6);  BARRIER(); COMPUTE(30); BARRIER();
    VMW(0);  BARRIER(); COMPUTE(31);
    __syncthreads();

    // ---- fused RMSNorm+RoPE on the K tile only (f32 acc, once per row) ----
    if constexpr (NORM) {
        if (n0 == 1024) {                 // K heads (cols 1024-1279); wave=head
            // stage rc/rs rows (m0&255)..+127 into LDS, stride-36 f32 (R9)
            float* rcL = (float*)(smem + 6144);       // byte 12288
            float* rsL = rcL + 4608;                  // 128*36 f32 each
            const float4* rcg = (const float4*)(rc + (m0 & 255) * 32);
            const float4* rsg = (const float4*)(rs + (m0 & 255) * 32);
#pragma unroll
            for (int p = 0; p < 4; ++p) {
                int ii = t + p * 256;                 // 1024 float4 total
                int row = ii >> 3, col = (ii & 7) * 4;
                float4 vc = rcg[ii];
                float4 vsn = rsg[ii];
                *(float4*)(&rcL[row * 36 + col]) = vc;
                *(float4*)(&rsL[row * 36 + col]) = vsn;
            }
            __syncthreads();
            const float s0 = ksc[m],      s1 = ksc[16 + m];
            const float s2 = ksc[32 + m], s3 = ksc[48 + m];
#pragma unroll
            for (int i = 0; i < 8; ++i) {
                float sq[4];
#pragma unroll
                for (int r = 0; r < 4; ++r)
                    sq[r] = acc[i][0][r] * acc[i][0][r] + acc[i][1][r] * acc[i][1][r]
                          + acc[i][2][r] * acc[i][2][r] + acc[i][3][r] * acc[i][3][r];
#pragma unroll
                for (int msk = 1; msk < 16; msk <<= 1)
#pragma unroll
                    for (int r = 0; r < 4; ++r) sq[r] += __shfl_xor(sq[r], msk);
#pragma unroll
                for (int r = 0; r < 4; ++r) {
                    float rrv = rsqrtf(sq[r] * (1.f / 64.f) + 1e-6f);
                    int rowL = i * 16 + quad * 4 + r;          // 0..127
                    float c0 = rcL[rowL * 36 + m],      sn0 = rsL[rowL * 36 + m];
                    float c1 = rcL[rowL * 36 + 16 + m], sn1 = rsL[rowL * 36 + 16 + m];
                    float a0 = acc[i][0][r] * rrv * s0;
                    float a1 = acc[i][1][r] * rrv * s1;
                    float a2 = acc[i][2][r] * rrv * s2;
                    float a3 = acc[i][3][r] * rrv * s3;
                    acc[i][0][r] = a0 * c0 - a2 * sn0;   // hd = m      (<32)
                    acc[i][1][r] = a1 * c1 - a3 * sn1;   // hd = 16+m   (<32)
                    acc[i][2][r] = a2 * c0 + a0 * sn0;   // hd = 32+m
                    acc[i][3][r] = a3 * c1 + a1 * sn1;   // hd = 48+m
                }
            }
        }
    }

    // epilogue: per-wave LDS transpose -> coalesced 16-elem stores
    const int row2 = lane >> 2, cb = lane & 3;
    if constexpr (sizeof(OUT) == 2) {
        __bf16* tile = smem + w * (16 * 68);
#pragma unroll
        for (int i = 0; i < 8; ++i) {
#pragma unroll
            for (int j = 0; j < 4; ++j)
#pragma unroll
                for (int r = 0; r < 4; ++r)
                    tile[(quad * 4 + r) * 68 + j * 16 + m] = (__bf16)acc[i][j][r];
            __bf16* dst = (__bf16*)C + (long)(m0 + i * 16 + row2) * N + n0 + wn + cb * 16;
            *(v8bf*)dst = *(const v8bf*)(&tile[row2 * 68 + cb * 16]);
            *(v8bf*)(dst + 8) = *(const v8bf*)(&tile[row2 * 68 + cb * 16 + 8]);
        }
    } else {
        float* tile = (float*)smem + w * (16 * 66);
#pragma unroll
        for (int i = 0; i < 8; ++i) {
#pragma unroll
            for (int j = 0; j < 4; ++j)
#pragma unroll
                for (int r = 0; r < 4; ++r)
                    tile[(quad * 4 + r) * 66 + j * 16 + m] = acc[i][j][r];
            float* dst = (float*)C + (long)(m0 + i * 16 + row2) * N + n0 + wn + cb * 16;
#pragma unroll
            for (int c = 0; c < 4; ++c)
                *(floatx4*)(dst + c * 4) = *(const floatx4*)(&tile[row2 * 66 + cb * 16 + c * 4]);
        }
    }
}

// ---------------------------------------------------------------- attention
// R12: K arrives PRE-NORMED+ROPED from the QKV epilogue (K-tile-only norm)
// -> K staging is a plain swizzled copy (R8, measured).  Q-norm stays here
// (R7 in-register form, 2 shfls).  R5-proven V^T slot perm
// perm = sgi ^ (hd&7) ^ (hd>>3); fma-folded bounded softmax.
__global__ __launch_bounds__(512) void attn_kernel(const __bf16* __restrict__ qkv,
                                                   const float* __restrict__ rc,
                                                   const float* __restrict__ rs,
                                                   const float* __restrict__ qsc,
                                                   __bf16* __restrict__ O) {
    __shared__ __attribute__((aligned(16))) __bf16 KV[256 * 64];  // K, then V^T
    __shared__ __attribute__((aligned(16))) __bf16 Ps[8][16][40];
    const int bx = blockIdx.x;
    const int n = bx >> 5, h = (bx >> 1) & 15, half = bx & 1, hk = h >> 2;
    const int t = threadIdx.x, lane = t & 63, w = t >> 6;
    const int m = lane & 15, quad = lane >> 4;

    // stage K rows [s][hd] (pre-normed), 8-elem groups swizzled by s&7
    for (int p = 0; p < 4; ++p) {
        int l = t + p * 512;
        int s = l >> 3, cg = l & 7;
        v8bf kv = *(const v8bf*)(qkv + (long)(n * 256 + s) * 1536 + 1024 + hk * 64 + cg * 8);
        *(v8bf*)(&KV[s * 64 + ((cg ^ (s & 7)) * 8)]) = kv;
    }
    // Q frag: load raw q, then rmsnorm+rope in-register (R7)
    const int srow = half * 128 + w * 16 + m;
    const __bf16* qp = qkv + (long)(n * 256 + srow) * 1536 + h * 64 + quad * 8;
    v8bf qr0 = *(const v8bf*)(qp);
    v8bf qr1 = *(const v8bf*)(qp + 32);
    float f0[8], f1[8], ss = 0.f;
#pragma unroll
    for (int j = 0; j < 8; ++j) {
        f0[j] = (float)qr0[j]; f1[j] = (float)qr1[j];
        ss += f0[j] * f0[j] + f1[j] * f1[j];
    }
    ss += __shfl_xor(ss, 16);
    ss += __shfl_xor(ss, 32);
    float rr = rsqrtf(ss * (1.f / 64.f) + 1e-6f);
    v8bf qa0, qa1;
#pragma unroll
    for (int j = 0; j < 8; ++j) {
        int hd = quad * 8 + j;
        float t1 = f0[j] * rr * qsc[hd];
        float t2 = f1[j] * rr * qsc[32 + hd];
        float c = rc[srow * 32 + hd], sn = rs[srow * 32 + hd];
        qa0[j] = (__bf16)(t1 * c - t2 * sn);
        qa1[j] = (__bf16)(t2 * c + t1 * sn);
    }
    __syncthreads();

    floatx4 sc[16];
#pragma unroll
    for (int ti = 0; ti < 16; ++ti) {
        int kr = ti * 16 + m;
        v8bf b0 = *(const v8bf*)(&KV[kr * 64 + ((quad ^ (kr & 7)) * 8)]);
        v8bf b1 = *(const v8bf*)(&KV[kr * 64 + (((quad + 4) ^ (kr & 7)) * 8)]);
        floatx4 a = {0.f, 0.f, 0.f, 0.f};
        a = MFMA16(qa0, b0, a);
        a = MFMA16(qa1, b1, a);
        sc[ti] = a;
    }

    // p = exp(50*tanh(v*0.0025)) ; bounded -> no max-subtract; 1/sum deferred
    const int qbase = half * 128 + w * 16 + quad * 4;
    float sum[4] = {0.f, 0.f, 0.f, 0.f};
#pragma unroll
    for (int ti = 0; ti < 16; ++ti)
#pragma unroll
        for (int r = 0; r < 4; ++r) {
            float v = sc[ti][r];
            float e = __builtin_amdgcn_exp2f(v * 0.0072134752f);
            float p = __builtin_amdgcn_exp2f(
                fmaf(__builtin_amdgcn_rcpf(e + 1.f), -144.269504f, 72.134752f));
            if (ti == 15 && (qbase + r) < 240) p = 0.f;
            sc[ti][r] = p;
            sum[r] += p;
        }
    float inv[4];
#pragma unroll
    for (int r = 0; r < 4; ++r) {
#pragma unroll
        for (int msk = 1; msk < 16; msk <<= 1) sum[r] += __shfl_xor(sum[r], msk);
        inv[r] = __builtin_amdgcn_rcpf(sum[r]);
    }

    // stage V^T over K's LDS: Vt[hd][s]; slot perm = sgi ^ (hd&7) ^ (hd>>3)
    __syncthreads();
    for (int p = 0; p < 4; ++p) {
        int l = t + p * 512;
        int s = l >> 3, cg = l & 7;
        v8bf vv = *(const v8bf*)(qkv + (long)(n * 256 + s) * 1536 + 1280 + hk * 64 + cg * 8);
#pragma unroll
        for (int j = 0; j < 8; ++j)
            KV[(cg * 8 + j) * 256 + (((s >> 3) ^ j ^ cg) * 8) + (s & 7)] = vv[j];
    }
    __syncthreads();

    floatx4 oacc[4] = {};
#pragma unroll
    for (int kc = 0; kc < 8; ++kc) {
#pragma unroll
        for (int ht = 0; ht < 2; ++ht) {
            int ti = kc * 2 + ht;
#pragma unroll
            for (int r = 0; r < 4; ++r)
                Ps[w][quad * 4 + r][ht * 16 + m] = (__bf16)sc[ti][r];
        }
        v8bf pa = *(const v8bf*)(&Ps[w][m][quad * 8]);
#pragma unroll
        for (int ct = 0; ct < 4; ++ct) {
            int hd = ct * 16 + m;
            int sg = kc * 4 + quad;
            int sl = (sg ^ (hd & 7) ^ (hd >> 3)) & 31;
            v8bf vb = *(const v8bf*)(&KV[hd * 256 + sl * 8]);
            oacc[ct] = MFMA16(pa, vb, oacc[ct]);
        }
    }
#pragma unroll
    for (int ct = 0; ct < 4; ++ct)
#pragma unroll
        for (int r = 0; r < 4; ++r) {
            int qrow = half * 128 + w * 16 + quad * 4 + r;
            O[(long)(n * 256 + qrow) * 1024 + h * 64 + ct * 16 + m] =
                (__bf16)(oacc[ct][r] * inv[r]);
        }
}

// ---------------------------------------------------------------- launch
extern "C" void kernel_launch(void* const* d_in, const int* in_sizes, int n_in,
                              void* d_out, int out_size, void* d_ws, size_t ws_size,
                              hipStream_t stream) {
    const float* x  = (const float*)d_in[0];
    const float* rc = (const float*)d_in[2];
    const float* rs = (const float*)d_in[3];
    const float* Wq = (const float*)d_in[4];
    const float* Wk = (const float*)d_in[5];
    const float* Wv = (const float*)d_in[6];
    const float* Wo = (const float*)d_in[7];
    const float* qs = (const float*)d_in[8];
    const float* ks = (const float*)d_in[9];
    float* out = (float*)d_out;
    char* ws = (char*)d_ws;

    __bf16* x_bf    = (__bf16*)(ws);                       // 32MB
    __bf16* WqkvT   = (__bf16*)(ws + (32l << 20));         // 3MB  [1536][1024]
    __bf16* WoT     = (__bf16*)(ws + (35l << 20));         // 2MB  [1024][1024]
    __bf16* qkv_bf  = (__bf16*)(ws + (37l << 20));         // 48MB [16384][1536]
    __bf16* attn_bf = (__bf16*)(ws + (93l << 20));         // 32MB [16384][1024]

    // prep: blocks [0,640) transpose/cast weights, [640,4736) cast x
    prep<<<4736, 256, 0, stream>>>(x, x_bf, 16777216 / 4,
                                   Wq, Wk, Wv, Wo, WqkvT, WoT);
    // QKV GEMM; K-tile blocks (n0==1024) apply RMSNorm+RoPE in the epilogue
    gemm_bt<true, __bf16><<<dim3(6, 128), 256, 0, stream>>>(
        x_bf, WqkvT, qkv_bf, 1536, rc, rs, ks);
    attn_kernel<<<2048, 512, 0, stream>>>(qkv_bf, rc, rs, qs, attn_bf);
    gemm_bt<false, float><<<dim3(4, 128), 256, 0, stream>>>(
        attn_bf, WoT, out, 1024, nullptr, nullptr, nullptr);
}